// Round 4
// baseline (435.556 us; speedup 1.0000x reference)
//
#include <hip/hip_runtime.h>
#include <stdint.h>

typedef unsigned short u16;
typedef unsigned int u32;

using bf16x8 = __attribute__((ext_vector_type(8))) short;
using f32x4  = __attribute__((ext_vector_type(4))) float;

__device__ __forceinline__ float bf2f(u16 u) {
  union { u32 u; float f; } v; v.u = ((u32)u) << 16; return v.f;
}
__device__ __forceinline__ u16 f2bf(float f) {
  union { float f; u32 u; } v; v.f = f;
  u32 r = v.u + 0x7fffu + ((v.u >> 16) & 1u);  // round-to-nearest-even
  return (u16)(r >> 16);
}
__device__ __forceinline__ short f2bf_s(float f) { return (short)f2bf(f); }

// ------------- weight convert+transpose: fp32 in[R][C] -> bf16 out[C][R] -------------
__global__ __launch_bounds__(256) void transpose_f32_bf16(
    const float* __restrict__ in, u16* __restrict__ out, int R, int C) {
  __shared__ u16 tile[32][33];
  const int tx = threadIdx.x, ty = threadIdx.y;
  const int icol = blockIdx.x * 32 + tx;
  const int irow0 = blockIdx.y * 32;
  #pragma unroll
  for (int i = ty; i < 32; i += 8)
    tile[i][tx] = f2bf(in[(size_t)(irow0 + i) * C + icol]);
  __syncthreads();
  const int ocol = blockIdx.y * 32 + tx;
  const int orow0 = blockIdx.x * 32;
  #pragma unroll
  for (int i = ty; i < 32; i += 8)
    out[(size_t)(orow0 + i) * R + ocol] = tile[tx][i];
}

// ------- fused RMS scales + x conversion: s[row]=rsqrt(mean(x^2)+eps); xb=bf16(x) -------
__global__ __launch_bounds__(256) void rms_convert(
    const float* __restrict__ x, float* __restrict__ s, u16* __restrict__ xb, int K) {
  const int row = blockIdx.x;
  const float4* p = (const float4*)(x + (size_t)row * K);
  ushort4* q = (ushort4*)(xb + (size_t)row * K);
  float sum = 0.f;
  const int nvec = K >> 2;  // 4 fp32 per float4
  for (int i = threadIdx.x; i < nvec; i += 256) {
    float4 v = p[i];
    sum += v.x * v.x + v.y * v.y + v.z * v.z + v.w * v.w;
    ushort4 o;
    o.x = f2bf(v.x); o.y = f2bf(v.y); o.z = f2bf(v.z); o.w = f2bf(v.w);
    q[i] = o;
  }
  #pragma unroll
  for (int off = 32; off > 0; off >>= 1) sum += __shfl_down(sum, off, 64);
  __shared__ float part[4];
  if ((threadIdx.x & 63) == 0) part[threadIdx.x >> 6] = sum;
  __syncthreads();
  if (threadIdx.x == 0) {
    float tot = part[0] + part[1] + part[2] + part[3];
    s[row] = rsqrtf(tot / (float)K + 1.1920928955078125e-07f);
  }
}

// ---------------- GEMM: C[M][N] = A[M][K] @ BT[N][K]^T  (+ epilogue) ----------------
// A, BT are bf16; bias/rowscale fp32; output bf16 (intermediates) or fp32 (final).
// EPI 0: v = acc*rowscale[row] + bias[col]           (GEMM1: RMS fold)
// EPI 1: v = acc + bias[col]; strictly-upper mask    (GEMM2, N==256)
// EPI 2: v = acc + bias[col]                         (GEMM3)
template <int EPI, bool OUTF32>
__global__ __launch_bounds__(256) void gemm_bt(
    const u16* __restrict__ A, const u16* __restrict__ BT,
    const float* __restrict__ bias, const float* __restrict__ rowscale,
    void* __restrict__ Cv, int M, int N, int K) {
  __shared__ u16 As[128 * 32];
  __shared__ u16 Bs[128 * 32];
  const int t = threadIdx.x;
  const int lane = t & 63;
  const int w = t >> 6;
  const int wm = (w >> 1) * 64;
  const int wn = (w & 1) * 64;
  const int quad = lane >> 4;
  const int lrow = lane & 15;
  const int m0 = blockIdx.y * 128;
  const int n0 = blockIdx.x * 128;

  f32x4 acc[4][4] = {};

  const int srow = t >> 2;          // staging row within 64-row round
  const int scol = (t & 3) * 8;     // staging k-offset (8 bf16 = 16 B)
  const size_t abase = (size_t)(m0 + srow) * K + scol;
  const size_t bbase = (size_t)(n0 + srow) * K + scol;
  u16* const as_lo = As + srow * 32 + scol;
  u16* const as_hi = As + (64 + srow) * 32 + scol;
  u16* const bs_lo = Bs + srow * 32 + scol;
  u16* const bs_hi = Bs + (64 + srow) * 32 + scol;

  for (int k0 = 0; k0 < K; k0 += 32) {
    const bf16x8 ra0 = *(const bf16x8*)(A + abase + k0);
    const bf16x8 ra1 = *(const bf16x8*)(A + abase + (size_t)64 * K + k0);
    const bf16x8 rb0 = *(const bf16x8*)(BT + bbase + k0);
    const bf16x8 rb1 = *(const bf16x8*)(BT + bbase + (size_t)64 * K + k0);
    __syncthreads();  // previous iteration's ds_reads complete before overwrite
    *(bf16x8*)as_lo = ra0;
    *(bf16x8*)as_hi = ra1;
    *(bf16x8*)bs_lo = rb0;
    *(bf16x8*)bs_hi = rb1;
    __syncthreads();

    bf16x8 af[4], bv[4];
    #pragma unroll
    for (int i = 0; i < 4; ++i)
      af[i] = *(const bf16x8*)(As + (wm + i * 16 + lrow) * 32 + quad * 8);
    #pragma unroll
    for (int j = 0; j < 4; ++j)
      bv[j] = *(const bf16x8*)(Bs + (wn + j * 16 + lrow) * 32 + quad * 8);
    #pragma unroll
    for (int i = 0; i < 4; ++i)
      #pragma unroll
      for (int j = 0; j < 4; ++j)
        acc[i][j] = __builtin_amdgcn_mfma_f32_16x16x32_bf16(af[i], bv[j], acc[i][j], 0, 0, 0);
  }

  // epilogue: C-layout col = lane&15, row = quad*4 + r
  #pragma unroll
  for (int i = 0; i < 4; ++i) {
    const int row0 = m0 + wm + i * 16 + quad * 4;
    float sc[4];
    if (EPI == 0) {
      #pragma unroll
      for (int r = 0; r < 4; ++r) sc[r] = rowscale[row0 + r];
    }
    #pragma unroll
    for (int j = 0; j < 4; ++j) {
      const int col = n0 + wn + j * 16 + lrow;
      const float bvs = bias[col];
      #pragma unroll
      for (int r = 0; r < 4; ++r) {
        float v = acc[i][j][r];
        if (EPI == 0) v = v * sc[r] + bvs;
        else v += bvs;
        if (EPI == 1) {
          const int cc = col & 255;  // N==256 here: flat idx = i16*16 + j16
          if ((cc & 15) <= (cc >> 4)) v = 0.f;  // keep strictly upper (j16 > i16)
        }
        const size_t idx = (size_t)(row0 + r) * N + col;
        if (OUTF32) ((float*)Cv)[idx] = v;
        else        ((u16*)Cv)[idx] = f2bf(v);
      }
    }
  }
}

// ---------------- per-row 16x16 expm via Taylor (exact: M nilpotent, M^16=0) ----------------
// One wave per row (4 rows/block). Left recurrence: term_k = (M * term_{k-1}) / k.
// M fixed in A-frag; term in B-frag. C-layout -> B-frag transform goes through LDS
// with a real __syncthreads() each iteration (ping-pong buffers, barriers block-uniform).
__global__ __launch_bounds__(256) void expm_taylor(
    const u16* __restrict__ Mi, u16* __restrict__ Eo) {
  __shared__ u16 mbuf[4][256];
  __shared__ float stage[2][4][16][17];
  const int t = threadIdx.x;
  const int w = t >> 6;
  const int lane = t & 63;
  const int q = lane >> 4;
  const int c = lane & 15;
  const size_t row = (size_t)blockIdx.x * 4 + w;

  *(uint2*)&mbuf[w][lane * 4] = *(const uint2*)(Mi + row * 256 + lane * 4);
  __syncthreads();

  const u16* mb = mbuf[w];
  const bf16x8 z8 = {0, 0, 0, 0, 0, 0, 0, 0};
  bf16x8 afrM = z8;  // A[m=c][k=q*8+jj] = M[c][q*8+jj], zero-padded K 16->32 (q>=2)
  bf16x8 bfr  = z8;  // B[k=q*8+jj][n=c] = term[q*8+jj][c], init term = M
  if (q < 2) {
    #pragma unroll
    for (int jj = 0; jj < 8; ++jj) {
      afrM[jj] = (short)mb[c * 16 + q * 8 + jj];
      bfr[jj]  = (short)mb[(q * 8 + jj) * 16 + c];
    }
  }
  // res = I + M  (C-layout: entry (q*4+r, c))
  float res[4];
  #pragma unroll
  for (int r = 0; r < 4; ++r) {
    const int rw = q * 4 + r;
    res[r] = (rw == c ? 1.f : 0.f) + bf2f(mb[rw * 16 + c]);
  }

  for (int k = 2; k <= 15; ++k) {
    const f32x4 z = {0.f, 0.f, 0.f, 0.f};
    f32x4 P = __builtin_amdgcn_mfma_f32_16x16x32_bf16(afrM, bfr, z, 0, 0, 0);
    const float inv = 1.0f / (float)k;
    float tv[4];
    #pragma unroll
    for (int r = 0; r < 4; ++r) { tv[r] = P[r] * inv; res[r] += tv[r]; }
    if (k < 15) {
      // C-layout -> LDS: entry (q*4+r, c); barrier; reload B-frag rows q*8+jj.
      // Ping-pong buffers => one block-uniform barrier per iteration suffices.
      #pragma unroll
      for (int r = 0; r < 4; ++r) stage[k & 1][w][q * 4 + r][c] = tv[r];
      __syncthreads();
      bfr = z8;
      if (q < 2) {
        #pragma unroll
        for (int jj = 0; jj < 8; ++jj) bfr[jj] = f2bf_s(stage[k & 1][w][q * 8 + jj][c]);
      }
    }
  }
  #pragma unroll
  for (int r = 0; r < 4; ++r)
    Eo[row * 256 + (size_t)(q * 4 + r) * 16 + c] = f2bf(res[r]);
}

extern "C" void kernel_launch(void* const* d_in, const int* in_sizes, int n_in,
                              void* d_out, int out_size, void* d_ws, size_t ws_size,
                              hipStream_t stream) {
  (void)in_sizes; (void)n_in; (void)out_size; (void)ws_size;
  // Inputs are FLOAT32 per the reference (jnp.float32) — reading them as bf16 was
  // the NaN source in rounds 0-3 (odd u16s = raw mantissa words => exponent 0xFF).
  const float* x   = (const float*)d_in[0];
  const float* W_u = (const float*)d_in[1];
  const float* b_u = (const float*)d_in[2];
  const float* W_t = (const float*)d_in[3];
  const float* b_t = (const float*)d_in[4];
  const float* W_s = (const float*)d_in[5];
  const float* b_s = (const float*)d_in[6];
  float* out = (float*)d_out;  // output fp32 (reference output dtype)

  // d_out is 128 MiB (8192*4096 fp32) — dead until GEMM3; use it as scratch:
  //   xb     bf16[8192][4096] at +0      (64 MiB)
  //   latent bf16[8192][1024] at +64MiB  (16 MiB)
  //   mmat   bf16[8192][256]  at +80MiB  (4 MiB)
  u16* xb     = (u16*)d_out;
  u16* latent = xb + (size_t)8192 * 4096;
  u16* mmat   = latent + (size_t)8192 * 1024;

  char* ws = (char*)d_ws;  // ~14.5 MiB total
  size_t off = 0;
  float* sscale = (float*)(ws + off); off += (size_t)8192 * sizeof(float);
  u16* WuT  = (u16*)(ws + off); off += (size_t)1024 * 4096 * 2;  // 8 MiB
  u16* WtT  = (u16*)(ws + off); off += (size_t)256 * 1024 * 2;   // 0.5 MiB
  u16* WsT  = (u16*)(ws + off); off += (size_t)4096 * 256 * 2;   // 2 MiB
  u16* eexp = (u16*)(ws + off); off += (size_t)8192 * 256 * 2;   // 4 MiB

  const dim3 tb(32, 8);
  // W_u[4096][1024] -> WuT[1024][4096]; W_t[1024][256] -> WtT; W_s[256][4096] -> WsT
  transpose_f32_bf16<<<dim3(1024 / 32, 4096 / 32), tb, 0, stream>>>(W_u, WuT, 4096, 1024);
  transpose_f32_bf16<<<dim3(256 / 32, 1024 / 32), tb, 0, stream>>>(W_t, WtT, 1024, 256);
  transpose_f32_bf16<<<dim3(4096 / 32, 256 / 32), tb, 0, stream>>>(W_s, WsT, 256, 4096);

  // sscale[row] = rsqrt(mean(x^2)+eps); xb = bf16(x)
  rms_convert<<<8192, 256, 0, stream>>>(x, sscale, xb, 4096);

  // latent = diag(s)*(xb @ W_u) + b_u   [8192,1024] bf16
  gemm_bt<0, false><<<dim3(1024 / 128, 8192 / 128), 256, 0, stream>>>(
      xb, WuT, b_u, sscale, latent, 8192, 1024, 4096);
  // mmat = mask(latent @ W_t + b_t)     [8192,256] bf16
  gemm_bt<1, false><<<dim3(256 / 128, 8192 / 128), 256, 0, stream>>>(
      latent, WtT, b_t, nullptr, mmat, 8192, 256, 1024);
  // eexp = expm(mmat)                    [8192,256] bf16 (ws)
  expm_taylor<<<8192 / 4, 256, 0, stream>>>(mmat, eexp);
  // out = eexp @ W_s + b_s               [8192,4096] fp32 (overwrites scratch, now dead)
  gemm_bt<2, true><<<dim3(4096 / 128, 8192 / 128), 256, 0, stream>>>(
      eexp, WsT, b_s, nullptr, out, 8192, 4096, 256);
}

// Round 5
// 431.277 us; speedup vs baseline: 1.0099x; 1.0099x over previous
//
#include <hip/hip_runtime.h>
#include <stdint.h>

typedef unsigned short u16;
typedef unsigned int u32;

using bf16x8 = __attribute__((ext_vector_type(8))) short;
using f32x4  = __attribute__((ext_vector_type(4))) float;

#define GLOBAL_AS __attribute__((address_space(1)))
#define LDS_AS    __attribute__((address_space(3)))

// bank swizzle: LDS slot s of row r holds global k-group s ^ SWZ(r); readers of
// k-group q use slot q ^ SWZ(r). Spreads quad reads over all 8 4-bank windows.
#define SWZ(r) (((r) >> 1) & 3)

__device__ __forceinline__ float bf2f(u16 u) {
  union { u32 u; float f; } v; v.u = ((u32)u) << 16; return v.f;
}
__device__ __forceinline__ u16 f2bf(float f) {
  union { float f; u32 u; } v; v.f = f;
  u32 r = v.u + 0x7fffu + ((v.u >> 16) & 1u);  // round-to-nearest-even
  return (u16)(r >> 16);
}
__device__ __forceinline__ short f2bf_s(float f) { return (short)f2bf(f); }

// ------------- weight convert+transpose: fp32 in[R][C] -> bf16 out[C][R] -------------
__global__ __launch_bounds__(256) void transpose_f32_bf16(
    const float* __restrict__ in, u16* __restrict__ out, int R, int C) {
  __shared__ u16 tile[32][33];
  const int tx = threadIdx.x, ty = threadIdx.y;
  const int icol = blockIdx.x * 32 + tx;
  const int irow0 = blockIdx.y * 32;
  #pragma unroll
  for (int i = ty; i < 32; i += 8)
    tile[i][tx] = f2bf(in[(size_t)(irow0 + i) * C + icol]);
  __syncthreads();
  const int ocol = blockIdx.y * 32 + tx;
  const int orow0 = blockIdx.x * 32;
  #pragma unroll
  for (int i = ty; i < 32; i += 8)
    out[(size_t)(orow0 + i) * R + ocol] = tile[tx][i];
}

// ------- fused RMS scales + x conversion: s[row]=rsqrt(mean(x^2)+eps); xb=bf16(x) -------
__global__ __launch_bounds__(256) void rms_convert(
    const float* __restrict__ x, float* __restrict__ s, u16* __restrict__ xb, int K) {
  const int row = blockIdx.x;
  const float4* p = (const float4*)(x + (size_t)row * K);
  ushort4* q = (ushort4*)(xb + (size_t)row * K);
  float sum = 0.f;
  const int nvec = K >> 2;  // 4 fp32 per float4
  for (int i = threadIdx.x; i < nvec; i += 256) {
    float4 v = p[i];
    sum += v.x * v.x + v.y * v.y + v.z * v.z + v.w * v.w;
    ushort4 o;
    o.x = f2bf(v.x); o.y = f2bf(v.y); o.z = f2bf(v.z); o.w = f2bf(v.w);
    q[i] = o;
  }
  #pragma unroll
  for (int off = 32; off > 0; off >>= 1) sum += __shfl_down(sum, off, 64);
  __shared__ float part[4];
  if ((threadIdx.x & 63) == 0) part[threadIdx.x >> 6] = sum;
  __syncthreads();
  if (threadIdx.x == 0) {
    float tot = part[0] + part[1] + part[2] + part[3];
    s[row] = rsqrtf(tot / (float)K + 1.1920928955078125e-07f);
  }
}

// ---------------- GEMM: C[M][N] = A[M][K] @ BT[N][K]^T  (+ epilogue) ----------------
// m97-style staging: __builtin_amdgcn_global_load_lds width=16 (async DMA, no VGPR
// round-trip) + XOR bank swizzle on the k-group slot (8-way -> 2-way ds_read_b128).
// EPI 0: v = acc*rowscale[row] + bias[col]           (GEMM1: RMS fold)
// EPI 1: v = acc + bias[col]; strictly-upper mask    (GEMM2, N==256)
// EPI 2: v = acc + bias[col]                         (GEMM3)
template <int EPI, bool OUTF32>
__global__ __launch_bounds__(256) void gemm_bt(
    const u16* __restrict__ A, const u16* __restrict__ BT,
    const float* __restrict__ bias, const float* __restrict__ rowscale,
    void* __restrict__ Cv, int M, int N, int K) {
  __shared__ u16 As[128 * 32];
  __shared__ u16 Bs[128 * 32];
  const int t = threadIdx.x;
  const int lane = t & 63;
  const int w = t >> 6;
  const int wm = (w >> 1) * 64;
  const int wn = (w & 1) * 64;
  const int quad = lane >> 4;
  const int lrow = lane & 15;
  const int m0 = blockIdx.y * 128;
  const int n0 = blockIdx.x * 128;

  f32x4 acc[4][4] = {};

  const int srow = t >> 2;                      // staging row within 64-row round
  const int sg   = (t & 3) ^ SWZ(srow);         // global k-group feeding this LDS slot
  const size_t abase = (size_t)(m0 + srow) * K + sg * 8;
  const size_t bbase = (size_t)(n0 + srow) * K + sg * 8;

  for (int k0 = 0; k0 < K; k0 += 32) {
    __syncthreads();  // previous iteration's ds_reads complete before overwrite
    #pragma unroll
    for (int r = 0; r < 2; ++r) {
      const u16* ga = A + abase + (size_t)r * 64 * K + k0;
      const u16* gb = BT + bbase + (size_t)r * 64 * K + k0;
      __builtin_amdgcn_global_load_lds((const GLOBAL_AS u32*)ga,
          (LDS_AS u32*)((u32*)As + r * 1024 + t * 4), 16, 0, 0);
      __builtin_amdgcn_global_load_lds((const GLOBAL_AS u32*)gb,
          (LDS_AS u32*)((u32*)Bs + r * 1024 + t * 4), 16, 0, 0);
    }
    __syncthreads();

    bf16x8 af[4], bv[4];
    #pragma unroll
    for (int i = 0; i < 4; ++i)
      af[i] = *(const bf16x8*)(As + (wm + i * 16 + lrow) * 32 + (quad ^ SWZ(lrow)) * 8);
    #pragma unroll
    for (int j = 0; j < 4; ++j)
      bv[j] = *(const bf16x8*)(Bs + (wn + j * 16 + lrow) * 32 + (quad ^ SWZ(lrow)) * 8);
    #pragma unroll
    for (int i = 0; i < 4; ++i)
      #pragma unroll
      for (int j = 0; j < 4; ++j)
        acc[i][j] = __builtin_amdgcn_mfma_f32_16x16x32_bf16(af[i], bv[j], acc[i][j], 0, 0, 0);
  }

  // epilogue: C-layout col = lane&15, row = quad*4 + r
  #pragma unroll
  for (int i = 0; i < 4; ++i) {
    const int row0 = m0 + wm + i * 16 + quad * 4;
    float sc[4];
    if (EPI == 0) {
      #pragma unroll
      for (int r = 0; r < 4; ++r) sc[r] = rowscale[row0 + r];
    }
    #pragma unroll
    for (int j = 0; j < 4; ++j) {
      const int col = n0 + wn + j * 16 + lrow;
      const float bvs = bias[col];
      #pragma unroll
      for (int r = 0; r < 4; ++r) {
        float v = acc[i][j][r];
        if (EPI == 0) v = v * sc[r] + bvs;
        else v += bvs;
        if (EPI == 1) {
          const int cc = col & 255;  // N==256 here: flat idx = i16*16 + j16
          if ((cc & 15) <= (cc >> 4)) v = 0.f;  // keep strictly upper (j16 > i16)
        }
        const size_t idx = (size_t)(row0 + r) * N + col;
        if (OUTF32) ((float*)Cv)[idx] = v;
        else        ((u16*)Cv)[idx] = f2bf(v);
      }
    }
  }
}

// ---------------- per-row 16x16 expm via Taylor (exact: M nilpotent, M^16=0) ----------------
// One wave per row (4 rows/block). Left recurrence: term_k = (M * term_{k-1}) / k.
// M fixed in A-frag; term in B-frag. C-layout -> B-frag transform goes through LDS
// with a real __syncthreads() each iteration (ping-pong buffers, barriers block-uniform).
__global__ __launch_bounds__(256) void expm_taylor(
    const u16* __restrict__ Mi, u16* __restrict__ Eo) {
  __shared__ u16 mbuf[4][256];
  __shared__ float stage[2][4][16][17];
  const int t = threadIdx.x;
  const int w = t >> 6;
  const int lane = t & 63;
  const int q = lane >> 4;
  const int c = lane & 15;
  const size_t row = (size_t)blockIdx.x * 4 + w;

  *(uint2*)&mbuf[w][lane * 4] = *(const uint2*)(Mi + row * 256 + lane * 4);
  __syncthreads();

  const u16* mb = mbuf[w];
  const bf16x8 z8 = {0, 0, 0, 0, 0, 0, 0, 0};
  bf16x8 afrM = z8;  // A[m=c][k=q*8+jj] = M[c][q*8+jj], zero-padded K 16->32 (q>=2)
  bf16x8 bfr  = z8;  // B[k=q*8+jj][n=c] = term[q*8+jj][c], init term = M
  if (q < 2) {
    #pragma unroll
    for (int jj = 0; jj < 8; ++jj) {
      afrM[jj] = (short)mb[c * 16 + q * 8 + jj];
      bfr[jj]  = (short)mb[(q * 8 + jj) * 16 + c];
    }
  }
  // res = I + M  (C-layout: entry (q*4+r, c))
  float res[4];
  #pragma unroll
  for (int r = 0; r < 4; ++r) {
    const int rw = q * 4 + r;
    res[r] = (rw == c ? 1.f : 0.f) + bf2f(mb[rw * 16 + c]);
  }

  for (int k = 2; k <= 15; ++k) {
    const f32x4 z = {0.f, 0.f, 0.f, 0.f};
    f32x4 P = __builtin_amdgcn_mfma_f32_16x16x32_bf16(afrM, bfr, z, 0, 0, 0);
    const float inv = 1.0f / (float)k;
    float tv[4];
    #pragma unroll
    for (int r = 0; r < 4; ++r) { tv[r] = P[r] * inv; res[r] += tv[r]; }
    if (k < 15) {
      #pragma unroll
      for (int r = 0; r < 4; ++r) stage[k & 1][w][q * 4 + r][c] = tv[r];
      __syncthreads();
      bfr = z8;
      if (q < 2) {
        #pragma unroll
        for (int jj = 0; jj < 8; ++jj) bfr[jj] = f2bf_s(stage[k & 1][w][q * 8 + jj][c]);
      }
    }
  }
  #pragma unroll
  for (int r = 0; r < 4; ++r)
    Eo[row * 256 + (size_t)(q * 4 + r) * 16 + c] = f2bf(res[r]);
}

extern "C" void kernel_launch(void* const* d_in, const int* in_sizes, int n_in,
                              void* d_out, int out_size, void* d_ws, size_t ws_size,
                              hipStream_t stream) {
  (void)in_sizes; (void)n_in; (void)out_size; (void)ws_size;
  // Inputs are FLOAT32 per the reference (jnp.float32).
  const float* x   = (const float*)d_in[0];
  const float* W_u = (const float*)d_in[1];
  const float* b_u = (const float*)d_in[2];
  const float* W_t = (const float*)d_in[3];
  const float* b_t = (const float*)d_in[4];
  const float* W_s = (const float*)d_in[5];
  const float* b_s = (const float*)d_in[6];
  float* out = (float*)d_out;  // output fp32 (reference output dtype)

  // d_out is 128 MiB (8192*4096 fp32) — dead until GEMM3; use it as scratch:
  //   xb     bf16[8192][4096] at +0      (64 MiB)
  //   latent bf16[8192][1024] at +64MiB  (16 MiB)
  //   mmat   bf16[8192][256]  at +80MiB  (4 MiB)
  u16* xb     = (u16*)d_out;
  u16* latent = xb + (size_t)8192 * 4096;
  u16* mmat   = latent + (size_t)8192 * 1024;

  char* ws = (char*)d_ws;  // ~14.5 MiB total
  size_t off = 0;
  float* sscale = (float*)(ws + off); off += (size_t)8192 * sizeof(float);
  u16* WuT  = (u16*)(ws + off); off += (size_t)1024 * 4096 * 2;  // 8 MiB
  u16* WtT  = (u16*)(ws + off); off += (size_t)256 * 1024 * 2;   // 0.5 MiB
  u16* WsT  = (u16*)(ws + off); off += (size_t)4096 * 256 * 2;   // 2 MiB
  u16* eexp = (u16*)(ws + off); off += (size_t)8192 * 256 * 2;   // 4 MiB

  const dim3 tb(32, 8);
  // W_u[4096][1024] -> WuT[1024][4096]; W_t[1024][256] -> WtT; W_s[256][4096] -> WsT
  transpose_f32_bf16<<<dim3(1024 / 32, 4096 / 32), tb, 0, stream>>>(W_u, WuT, 4096, 1024);
  transpose_f32_bf16<<<dim3(256 / 32, 1024 / 32), tb, 0, stream>>>(W_t, WtT, 1024, 256);
  transpose_f32_bf16<<<dim3(4096 / 32, 256 / 32), tb, 0, stream>>>(W_s, WsT, 256, 4096);

  // sscale[row] = rsqrt(mean(x^2)+eps); xb = bf16(x)
  rms_convert<<<8192, 256, 0, stream>>>(x, sscale, xb, 4096);

  // latent = diag(s)*(xb @ W_u) + b_u   [8192,1024] bf16
  gemm_bt<0, false><<<dim3(1024 / 128, 8192 / 128), 256, 0, stream>>>(
      xb, WuT, b_u, sscale, latent, 8192, 1024, 4096);
  // mmat = mask(latent @ W_t + b_t)     [8192,256] bf16
  gemm_bt<1, false><<<dim3(256 / 128, 8192 / 128), 256, 0, stream>>>(
      latent, WtT, b_t, nullptr, mmat, 8192, 256, 1024);
  // eexp = expm(mmat)                    [8192,256] bf16 (ws)
  expm_taylor<<<8192 / 4, 256, 0, stream>>>(mmat, eexp);
  // out = eexp @ W_s + b_s               [8192,4096] fp32 (overwrites scratch, now dead)
  gemm_bt<2, true><<<dim3(4096 / 128, 8192 / 128), 256, 0, stream>>>(
      eexp, WsT, b_s, nullptr, out, 8192, 4096, 256);
}